// Round 2
// baseline (170.872 us; speedup 1.0000x reference)
//
#include <hip/hip_runtime.h>
#include <math.h>

#define DD 32
#define MM 16
#define TROW 80   // tbl row: t[32] | it[32] | cj[8] | pad[8]  (320B = 5 full cache lines)

typedef int          vi4 __attribute__((ext_vector_type(4)));
typedef unsigned int vu4 __attribute__((ext_vector_type(4)));

__device__ __forceinline__ void load8f4(const float* __restrict__ p, float* r) {
    const float4* q = (const float4*)p;
#pragma unroll
    for (int i = 0; i < 8; ++i) {
        float4 v = q[i];
        r[4*i+0] = v.x; r[4*i+1] = v.y; r[4*i+2] = v.z; r[4*i+3] = v.w;
    }
}

// One thread per (item, dim). All register-array accesses are compile-time
// (rule #20: runtime-indexed register arrays demote to scratch — the it[d]
// copy therefore RE-LOADS row[d] from global, which is L1-hot).
// tbl[i*80 + 0..31]  = t_i[d] = sum_e W_bil[d][e] * item_e[i][e]
// tbl[i*80 + 32..63] = item_e[i][d]
// tbl[i*80 + 64..71] = c_i[j] = sum_d W1[j][64+d] * item_e[i][d]
__global__ void precompute_item(const float* __restrict__ item_table,
                                const float* __restrict__ W_bil,
                                const float* __restrict__ W1,
                                float* __restrict__ tbl, int NI) {
    int g = blockIdx.x * blockDim.x + threadIdx.x;
    if (g >= NI * DD) return;
    int i = g >> 5;
    int d = g & (DD - 1);
    const float* row = item_table + (size_t)i * DD;
    float it[DD];
    load8f4(row, it);   // same-address across the 32 lanes of one item -> broadcast
    const float* w = W_bil + d * DD;
    float s0 = 0.f, s1 = 0.f, s2 = 0.f, s3 = 0.f;
#pragma unroll
    for (int e = 0; e < DD; e += 4) {
        s0 = fmaf(w[e+0], it[e+0], s0);
        s1 = fmaf(w[e+1], it[e+1], s1);
        s2 = fmaf(w[e+2], it[e+2], s2);
        s3 = fmaf(w[e+3], it[e+3], s3);
    }
    float* o = tbl + (size_t)i * TROW;
    o[d]      = (s0 + s1) + (s2 + s3);
    o[DD + d] = row[d];            // direct global re-load (L1 hit), NOT it[d]
    if (d < 8) {
        const float* w1 = W1 + d * 96 + 64;
        float c0 = 0.f, c1 = 0.f, c2 = 0.f, c3 = 0.f;
#pragma unroll
        for (int e = 0; e < DD; e += 4) {
            c0 = fmaf(w1[e+0], it[e+0], c0);
            c1 = fmaf(w1[e+1], it[e+1], c1);
            c2 = fmaf(w1[e+2], it[e+2], c2);
            c3 = fmaf(w1[e+3], it[e+3], c3);
        }
        o[64 + d] = (c0 + c1) + (c2 + c3);
    }
}

// One member: 4-way partial dot then fin accumulate.
__device__ __forceinline__ void member1(const float* __restrict__ ut, int id,
                                        const float* __restrict__ t, float bb,
                                        float* __restrict__ fin) {
    float me[DD];
    load8f4(ut + (size_t)id * DD, me);
    float s0 = 0.f, s1 = 0.f, s2 = 0.f, s3 = 0.f;
#pragma unroll
    for (int d = 0; d < DD; d += 4) {
        s0 = fmaf(me[d+0], t[d+0], s0);
        s1 = fmaf(me[d+1], t[d+1], s1);
        s2 = fmaf(me[d+2], t[d+2], s2);
        s3 = fmaf(me[d+3], t[d+3], s3);
    }
    float s = ((s0 + s1) + (s2 + s3)) + bb;
#pragma unroll
    for (int d = 0; d < DD; ++d) fin[d] = fmaf(s, me[d], fin[d]);
}

// Two members: both rows' loads issued back-to-back so B's latency hides under A's compute.
__device__ __forceinline__ void member2(const float* __restrict__ ut, int ia, int ib,
                                        const float* __restrict__ t, float bb,
                                        float* __restrict__ fin) {
    float ma[DD], mb[DD];
    load8f4(ut + (size_t)ia * DD, ma);
    load8f4(ut + (size_t)ib * DD, mb);
    float a0 = 0.f, a1 = 0.f, a2 = 0.f, a3 = 0.f;
    float c0 = 0.f, c1 = 0.f, c2 = 0.f, c3 = 0.f;
#pragma unroll
    for (int d = 0; d < DD; d += 4) {
        a0 = fmaf(ma[d+0], t[d+0], a0);
        a1 = fmaf(ma[d+1], t[d+1], a1);
        a2 = fmaf(ma[d+2], t[d+2], a2);
        a3 = fmaf(ma[d+3], t[d+3], a3);
        c0 = fmaf(mb[d+0], t[d+0], c0);
        c1 = fmaf(mb[d+1], t[d+1], c1);
        c2 = fmaf(mb[d+2], t[d+2], c2);
        c3 = fmaf(mb[d+3], t[d+3], c3);
    }
    float sa = ((a0 + a1) + (a2 + a3)) + bb;
    float sb = ((c0 + c1) + (c2 + c3)) + bb;
#pragma unroll
    for (int d = 0; d < DD; ++d) fin[d] = fmaf(sa, ma[d], fin[d]);
#pragma unroll
    for (int d = 0; d < DD; ++d) fin[d] = fmaf(sb, mb[d], fin[d]);
}

template <bool USE_TBL>
__global__ __launch_bounds__(256)
void bilinear_main(const int* __restrict__ item_inputs,
                   const int* __restrict__ member_ids,
                   const unsigned char* __restrict__ member_mask,
                   const float* __restrict__ user_table,
                   const float* __restrict__ item_table,
                   const float* __restrict__ tbl,
                   const float* __restrict__ W_bil,
                   const float* __restrict__ b_bil,
                   const float* __restrict__ W1,
                   const float* __restrict__ b1v,
                   const float* __restrict__ W2,
                   const float* __restrict__ b2v,
                   float* __restrict__ out, int Btot) {
    int b = blockIdx.x * blockDim.x + threadIdx.x;
    if (b >= Btot) return;

    // One-touch streams: nontemporal so they don't evict user_table/tbl from L2.
    int item = __builtin_nontemporal_load(item_inputs + b);

    vu4 mv = __builtin_nontemporal_load((const vu4*)(member_mask + (size_t)b * MM));
    int len = __popc(mv[0] & 0x01010101u) + __popc(mv[1] & 0x01010101u) +
              __popc(mv[2] & 0x01010101u) + __popc(mv[3] & 0x01010101u);

    const vi4* mp = (const vi4*)(member_ids + (size_t)b * MM);
    vi4 q0 = __builtin_nontemporal_load(mp + 0);
    vi4 q1 = __builtin_nontemporal_load(mp + 1);
    vi4 q2 = __builtin_nontemporal_load(mp + 2);
    vi4 q3 = __builtin_nontemporal_load(mp + 3);
    int ids[MM];
    ids[0]=q0[0];  ids[1]=q0[1];  ids[2]=q0[2];  ids[3]=q0[3];
    ids[4]=q1[0];  ids[5]=q1[1];  ids[6]=q1[2];  ids[7]=q1[3];
    ids[8]=q2[0];  ids[9]=q2[1];  ids[10]=q2[2]; ids[11]=q2[3];
    ids[12]=q3[0]; ids[13]=q3[1]; ids[14]=q3[2]; ids[15]=q3[3];

    float t[DD];
    const float* tb = nullptr;
    if (USE_TBL) {
        tb = tbl + (size_t)item * TROW;
        load8f4(tb, t);
    } else {
        float it0[DD];
        load8f4(item_table + (size_t)item * DD, it0);
#pragma unroll 4
        for (int d = 0; d < DD; ++d) {
            float s = 0.f;
#pragma unroll
            for (int e = 0; e < DD; ++e) s = fmaf(W_bil[d * DD + e], it0[e], s);
            t[d] = s;
        }
    }

    float bb = b_bil[0];
    float fin[DD];
#pragma unroll
    for (int d = 0; d < DD; ++d) fin[d] = 0.f;

    // Member loop: FULLY unrolled (compile-time pair index) so ids[] accesses
    // are constant-folded and the array stays in registers (no scratch).
    // Lanes diverge on len; masked iterations issue no memory requests.
#pragma unroll
    for (int p = 0; p < MM / 2; ++p) {
        int m = 2 * p;
        if (m + 1 < len)      member2(user_table, ids[m], ids[m + 1], t, bb, fin);
        else if (m < len)     member1(user_table, ids[m], t, bb, fin);
    }

    // Epilogue: it + cj.
    float it[DD];
    float cj[8];
    if (USE_TBL) {
        load8f4(tb + DD, it);
        float4 g0 = *(const float4*)(tb + 64);
        float4 g1 = *(const float4*)(tb + 68);
        cj[0] = g0.x; cj[1] = g0.y; cj[2] = g0.z; cj[3] = g0.w;
        cj[4] = g1.x; cj[5] = g1.y; cj[6] = g1.z; cj[7] = g1.w;
    } else {
        load8f4(item_table + (size_t)item * DD, it);
#pragma unroll
        for (int j = 0; j < 8; ++j) {
            float s = 0.f;
#pragma unroll
            for (int d = 0; d < DD; ++d) s = fmaf(W1[j * 96 + 64 + d], it[d], s);
            cj[j] = s;
        }
    }

    // MLP: h_j = relu(c_j + b1_j + sum_d W1[j,d]*(f*i)[d] + W1[j,32+d]*f[d])
    float h[8];
#pragma unroll
    for (int j = 0; j < 8; ++j) h[j] = cj[j] + b1v[j];
#pragma unroll
    for (int d = 0; d < DD; ++d) {
        float f = fin[d];
        float pfi = f * it[d];
#pragma unroll
        for (int j = 0; j < 8; ++j) {
            h[j] = fmaf(W1[j * 96 + d], pfi, h[j]);
            h[j] = fmaf(W1[j * 96 + 32 + d], f, h[j]);
        }
    }
    float z = b2v[0];
#pragma unroll
    for (int j = 0; j < 8; ++j) {
        float hv = h[j] > 0.f ? h[j] : 0.f;
        z = fmaf(W2[j], hv, z);
    }
    __builtin_nontemporal_store(1.f / (1.f + __expf(-z)), out + b);
}

extern "C" void kernel_launch(void* const* d_in, const int* in_sizes, int n_in,
                              void* d_out, int out_size, void* d_ws, size_t ws_size,
                              hipStream_t stream) {
    const int*           item_inputs = (const int*)d_in[0];
    const int*           member_ids  = (const int*)d_in[1];
    const unsigned char* member_mask = (const unsigned char*)d_in[2];
    const float*         user_table  = (const float*)d_in[3];
    const float*         item_table  = (const float*)d_in[4];
    const float*         W_bil       = (const float*)d_in[5];
    const float*         b_bil       = (const float*)d_in[6];
    const float*         W1          = (const float*)d_in[7];
    const float*         b1          = (const float*)d_in[8];
    const float*         W2          = (const float*)d_in[9];
    const float*         b2          = (const float*)d_in[10];
    float* out = (float*)d_out;

    int Btot = in_sizes[0];
    int NI   = in_sizes[4] / DD;

    bool use_tbl = ws_size >= (size_t)NI * TROW * sizeof(float);
    int blk = 256;
    if (use_tbl) {
        float* tbl = (float*)d_ws;
        precompute_item<<<(NI * DD + blk - 1) / blk, blk, 0, stream>>>(item_table, W_bil, W1, tbl, NI);
        bilinear_main<true><<<(Btot + blk - 1) / blk, blk, 0, stream>>>(
            item_inputs, member_ids, member_mask, user_table, item_table, tbl,
            W_bil, b_bil, W1, b1, W2, b2, out, Btot);
    } else {
        bilinear_main<false><<<(Btot + blk - 1) / blk, blk, 0, stream>>>(
            item_inputs, member_ids, member_mask, user_table, item_table, nullptr,
            W_bil, b_bil, W1, b1, W2, b2, out, Btot);
    }
}